// Round 7
// baseline (349.428 us; speedup 1.0000x reference)
//
#include <hip/hip_runtime.h>

typedef unsigned short u16;
typedef unsigned int u32;
typedef __attribute__((ext_vector_type(8))) short short8;    // 8 bf16 (4 VGPRs)
typedef __attribute__((ext_vector_type(16))) float floatx16; // 32x32 MFMA acc

__device__ __forceinline__ u16 f2bf(float f) {
  u32 u = __float_as_uint(f);
  u32 r = u + 0x7fffu + ((u >> 16) & 1u);   // round-to-nearest-even
  return (u16)(r >> 16);
}

// async global->LDS, 16B per lane. lds ptr must be wave-uniform base; HW
// writes lane i at base + i*16.
__device__ __forceinline__ void gload_lds16(const u16* g, u16* l) {
  __builtin_amdgcn_global_load_lds(
      (const __attribute__((address_space(1))) u32*)g,
      (__attribute__((address_space(3))) u32*)l, 16, 0, 0);
}

// ---------------------------------------------------------------------------
// Fused cast (fp32->bf16) + transpose tile worker. in: [rows, cols] fp32.
// cast_out (optional): bf16 same layout (ushort4 stores).
// tr_out: bf16 [cols, rows] (u32 = 2-element stores, coalesced along rows).
// Tile 64x64, 256 threads. tileT pad 66 (132B row, 33-bank shift).
// ---------------------------------------------------------------------------
__device__ __forceinline__ void cast_tr_tile(
    u16 (*tileT)[66], const float* __restrict__ in, u16* __restrict__ cast_out,
    u16* __restrict__ tr_out, int rows, int cols, float scale,
    int r0, int c0, int tid)
{
  // phase 1: read float4, cast, store ushort4, scatter to tileT
  {
    const int i0 = tid >> 4;          // 0..15 row group
    const int c4 = (tid & 15) * 4;    // col group of 4
    #pragma unroll
    for (int rr = 0; rr < 4; ++rr) {
      const int r = i0 + 16 * rr;
      const float4 v = *(const float4*)&in[(long)(r0 + r) * cols + c0 + c4];
      ushort4 h;
      h.x = f2bf(v.x * scale); h.y = f2bf(v.y * scale);
      h.z = f2bf(v.z * scale); h.w = f2bf(v.w * scale);
      if (cast_out)
        *(ushort4*)&cast_out[(long)(r0 + r) * cols + c0 + c4] = h;
      tileT[c4 + 0][r] = h.x;
      tileT[c4 + 1][r] = h.y;
      tileT[c4 + 2][r] = h.z;
      tileT[c4 + 3][r] = h.w;
    }
  }
  __syncthreads();

  // phase 2: write transposed, u32 (2 bf16) per store, lanes walk rows fast
  {
    const int cb = tid >> 5;          // 0..7
    const int rh = tid & 31;          // 0..31 (u32 position within 64 rows)
    #pragma unroll
    for (int m = 0; m < 8; ++m) {
      const int c = cb * 8 + m;
      const u32 pair = *(const u32*)&tileT[c][rh * 2];
      *(u32*)&tr_out[(long)(c0 + c) * rows + r0 + rh * 2] = pair;
    }
  }
}

// ---------------------------------------------------------------------------
// Single prep kernel: {rsum=0, cast_tr(x), cast_tr(W)} in one dispatch.
// Grid (16, 32, 9): z<8 -> x batch z; z=8,by<16 -> W; z=8,by==16 -> rsum.
// ---------------------------------------------------------------------------
__global__ __launch_bounds__(256)
void prep(const float* __restrict__ x, const float* __restrict__ W,
          u16* __restrict__ Xb, u16* __restrict__ XbT, u16* __restrict__ Wt,
          float* __restrict__ rsum)
{
  __shared__ u16 tileT[64][66];
  const int tid = threadIdx.x;
  const int bx = blockIdx.x, by = blockIdx.y, z = blockIdx.z;

  if (z < 8) {
    const long off = (long)z * 2048 * 1024;
    cast_tr_tile(tileT, x + off, Xb + off, XbT + off,
                 2048, 1024, 1.0f, by * 64, bx * 64, tid);
  } else if (by < 16) {
    cast_tr_tile(tileT, W, nullptr, Wt,
                 1024, 1024, 0.03125f, by * 64, bx * 64, tid);
  } else if (by == 16) {
    *(float4*)&rsum[(bx * 256 + tid) * 4] = (float4){0.f, 0.f, 0.f, 0.f};
  }
}

// ---------------------------------------------------------------------------
// NT GEMM: C[M,N] = A[M,K] * Bt[N,K]^T, bf16 inputs, fp32 accumulate.
// 128x128 block tile, BK=64, 4 waves in 2x2; each wave 64x64 = 2x2 frags of
// v_mfma_f32_32x32x16_bf16 (R7: was 16x16x32 — same LDS traffic, same 64
// acc regs, but MFMA pipe time/tile 155->129 cyc and instr count halved;
// µbench 2495 vs 2075 TF). Staging via global_load_lds(16B) + XOR chunk
// swizzle (read pattern still 2-way bank aliasing = free). GROUP_M=8 pid
// swizzle for L2 strip reuse.
//
// A/B frag (32x32x16): lane l holds row l&31, k = (l>>5)*8 + j  (same-family
// layout as the verified 16x16x32: contiguous 16B per lane).
// C/D frag: col = lane&31, row = (reg&3) + 8*(reg>>2) + 4*(lane>>5)  [m74].
//
// MODE 0: plain bf16 out.
// MODE 1: bf16 out = exp(acc*escale); fp32 row sums into rsum (atomics).
// MODE 2: fp32 out = acc / rsum[row] + bias[col].
// ---------------------------------------------------------------------------
#define BK 64

template<int MODE>
__global__ __launch_bounds__(256, 3)
void gemm_nt(const u16* __restrict__ A, const u16* __restrict__ Bt,
             void* __restrict__ Cout, const float* __restrict__ bias,
             float* __restrict__ rsum,
             int M, int N, int K, int lda, int ldb, int ldc,
             long sA, long sB, long sC, float escale)
{
  constexpr int BM = 128;
  constexpr int BN = 128;
  __shared__ __align__(16) u16 As[BM * BK];
  __shared__ __align__(16) u16 Bs[BN * BK];

  const int bz = blockIdx.z;
  A  += (long)bz * sA;
  Bt += (long)bz * sB;

  const int tid  = threadIdx.x;
  const int wave = tid >> 6;
  const int lane = tid & 63;

  // GROUP_M=8 swizzle
  const int nbx = gridDim.x, nby = gridDim.y;
  const int pid  = blockIdx.y * nbx + blockIdx.x;
  const int band = 8 * nbx;
  const int gid  = pid / band;
  const int fm   = gid * 8;
  const int gsz  = min(nby - fm, 8);
  const int pm   = fm + (pid % band) % gsz;
  const int pn   = (pid % band) / gsz;
  const int tileM = pm * BM;
  const int tileN = pn * BN;

  // staging: per instruction a wave covers 8 rows x 8 chunks (16B each)
  const int srow = lane >> 3;      // 0..7 row within 8-row group
  const int sj   = lane & 7;       // 0..7 dest chunk
  const int sjj  = sj ^ srow;      // swizzled source chunk

  // wave quadrant + mfma lane coords (32x32 frags)
  const int wm = (wave >> 1) * 64;
  const int wn = (wave & 1) * 64;
  const int lr = lane & 31;        // A row / B col / C col within frag
  const int hl = lane >> 5;        // k-half (input) / row-half (output)

  floatx16 acc[2][2];
  #pragma unroll
  for (int fi = 0; fi < 2; ++fi)
    #pragma unroll
    for (int fj = 0; fj < 2; ++fj)
      #pragma unroll
      for (int r = 0; r < 16; ++r)
        acc[fi][fj][r] = 0.f;

  for (int k0 = 0; k0 < K; k0 += BK) {
    #pragma unroll
    for (int s = 0; s < 4; ++s) {
      const int rb = (wave * 4 + s) * 8;
      gload_lds16(A + (long)(tileM + rb + srow) * lda + k0 + sjj * 8,
                  &As[rb * BK]);
    }
    #pragma unroll
    for (int s = 0; s < 4; ++s) {
      const int rb = (wave * 4 + s) * 8;
      gload_lds16(Bt + (long)(tileN + rb + srow) * ldb + k0 + sjj * 8,
                  &Bs[rb * BK]);
    }
    __syncthreads();   // drains vmcnt(0) -> LDS valid

    #pragma unroll
    for (int kk = 0; kk < BK; kk += 16) {
      const int jc = (kk >> 3) + hl;        // logical chunk for this k-half
      short8 af[2], bf[2];
      #pragma unroll
      for (int fi = 0; fi < 2; ++fi) {
        const int m = wm + fi * 32 + lr;
        af[fi] = *(const short8*)&As[m * BK + ((jc ^ (m & 7)) << 3)];
      }
      #pragma unroll
      for (int fj = 0; fj < 2; ++fj) {
        const int n = wn + fj * 32 + lr;
        bf[fj] = *(const short8*)&Bs[n * BK + ((jc ^ (n & 7)) << 3)];
      }
      #pragma unroll
      for (int fi = 0; fi < 2; ++fi)
        #pragma unroll
        for (int fj = 0; fj < 2; ++fj)
          acc[fi][fj] = __builtin_amdgcn_mfma_f32_32x32x16_bf16(
                            af[fi], bf[fj], acc[fi][fj], 0, 0, 0);
    }
    __syncthreads();   // protect LDS before next stage
  }

  // epilogue: C/D col = lane&31, row = (r&3) + 8*(r>>2) + 4*hl
  if (MODE == 0) {
    u16* C = (u16*)Cout + (long)bz * sC;
    #pragma unroll
    for (int fi = 0; fi < 2; ++fi) {
      const int rb = tileM + wm + fi * 32 + hl * 4;
      #pragma unroll
      for (int fj = 0; fj < 2; ++fj) {
        const int col = tileN + wn + fj * 32 + lr;
        #pragma unroll
        for (int r = 0; r < 16; ++r) {
          const int row = rb + (r & 3) + ((r >> 2) << 3);
          C[(long)row * ldc + col] = f2bf(acc[fi][fj][r]);
        }
      }
    }
  } else if (MODE == 1) {
    u16* C = (u16*)Cout + (long)bz * sC;
    float* rs = rsum + (long)bz * M;
    #pragma unroll
    for (int fi = 0; fi < 2; ++fi) {
      const int rb = tileM + wm + fi * 32 + hl * 4;
      float rpart[16];
      #pragma unroll
      for (int r = 0; r < 16; ++r) rpart[r] = 0.f;
      #pragma unroll
      for (int fj = 0; fj < 2; ++fj) {
        const int col = tileN + wn + fj * 32 + lr;
        #pragma unroll
        for (int r = 0; r < 16; ++r) {
          const int row = rb + (r & 3) + ((r >> 2) << 3);
          float e = __expf(acc[fi][fj][r] * escale);
          C[(long)row * ldc + col] = f2bf(e);
          rpart[r] += e;
        }
      }
      #pragma unroll
      for (int r = 0; r < 16; ++r) {
        float v = rpart[r];
        v += __shfl_xor(v, 1, 64);
        v += __shfl_xor(v, 2, 64);
        v += __shfl_xor(v, 4, 64);
        v += __shfl_xor(v, 8, 64);
        v += __shfl_xor(v, 16, 64);      // full 32-col sum within each half
        if (lr == 0) atomicAdd(&rs[rb + (r & 3) + ((r >> 2) << 3)], v);
      }
    }
  } else {
    float* C = (float*)Cout + (long)bz * sC;
    const float* rs = rsum + (long)bz * M;
    #pragma unroll
    for (int fi = 0; fi < 2; ++fi) {
      const int rb = tileM + wm + fi * 32 + hl * 4;
      float inv[16];
      #pragma unroll
      for (int r = 0; r < 16; ++r)
        inv[r] = 1.0f / rs[rb + (r & 3) + ((r >> 2) << 3)];
      #pragma unroll
      for (int fj = 0; fj < 2; ++fj) {
        const int col = tileN + wn + fj * 32 + lr;
        const float bv = bias[col];
        #pragma unroll
        for (int r = 0; r < 16; ++r) {
          const int row = rb + (r & 3) + ((r >> 2) << 3);
          C[(long)row * ldc + col] = acc[fi][fj][r] * inv[r] + bv;
        }
      }
    }
  }
}

// ---------------------------------------------------------------------------
extern "C" void kernel_launch(void* const* d_in, const int* in_sizes, int n_in,
                              void* d_out, int out_size, void* d_ws, size_t ws_size,
                              hipStream_t stream) {
  const float* x    = (const float*)d_in[0];   // [B,S,D] fp32
  const float* W    = (const float*)d_in[1];   // [D,D]   fp32
  const float* bias = (const float*)d_in[2];   // [D]     fp32
  float* out        = (float*)d_out;           // [B,S,D] fp32
  (void)in_sizes; (void)n_in; (void)out_size; (void)ws_size;

  const int B = 8, S = 2048, D = 1024;
  const long BSD = (long)B * S * D;            // 16,777,216

  // workspace layout (u16 elements): ~162 MiB + 64 KiB row sums
  u16* Xb  = (u16*)d_ws;            // [B,S,D] bf16 (x)
  u16* XbT = Xb  + BSD;             // [B,D,S] bf16 (x transposed per batch)
  u16* Qb  = XbT + BSD;             // [B,S,D] bf16 (Q, pre-scaled by 1/32)
  u16* Wt  = Qb  + BSD;             // [D,D]   bf16 (W^T * 1/sqrt(D))
  u16* Sc  = Wt  + (long)D * D;     // [B,S,S] bf16 (E = exp(scores), unnorm)
  float* rsum = (float*)(Sc + (long)B * S * S);  // [B,S] fp32 row sums

  dim3 blk(256);

  // prep: x->Xb+XbT, W->Wt (1/32 folded into Q), rsum=0 — one dispatch
  prep<<<dim3(D/64, S/64, B + 1), blk, 0, stream>>>(x, W, Xb, XbT, Wt, rsum);

  // GEMM1: Qb[BS,D] = Xb[BS,D] @ Wt[D,D]^T   (batches flattened)
  gemm_nt<0><<<dim3(D/128, (B*S)/128, 1), blk, 0, stream>>>(
      Xb, Wt, Qb, nullptr, nullptr, B*S, D, D, D, D, D, 0, 0, 0, 1.0f);

  // GEMM2: Sc[S,S] = exp(Qb[S,D] @ Xb[S,D]^T), rsum += row sums  per batch
  gemm_nt<1><<<dim3(S/128, S/128, B), blk, 0, stream>>>(
      Qb, Xb, Sc, nullptr, rsum, S, S, D, D, D, S,
      (long)S*D, (long)S*D, (long)S*S, 1.0f);

  // GEMM3: out[S,D] = (Sc/rsum)[S,S] @ XbT[D,S]^T + bias  per batch, fp32 out
  gemm_nt<2><<<dim3(D/128, S/128, B), blk, 0, stream>>>(
      Sc, XbT, out, bias, rsum, S, D, S, S, S, D,
      (long)S*S, (long)D*S, (long)S*D, 1.0f);
}

// Round 8
// 307.260 us; speedup vs baseline: 1.1372x; 1.1372x over previous
//
#include <hip/hip_runtime.h>

typedef unsigned short u16;
typedef unsigned int u32;
typedef __attribute__((ext_vector_type(8))) short short8;   // 8 bf16 (4 VGPRs)
typedef __attribute__((ext_vector_type(4))) float floatx4;  // MFMA accumulator

__device__ __forceinline__ u16 f2bf(float f) {
  u32 u = __float_as_uint(f);
  u32 r = u + 0x7fffu + ((u >> 16) & 1u);   // round-to-nearest-even
  return (u16)(r >> 16);
}

// async global->LDS, 16B per lane. lds ptr must be wave-uniform base; HW
// writes lane i at base + i*16.
__device__ __forceinline__ void gload_lds16(const u16* g, u16* l) {
  __builtin_amdgcn_global_load_lds(
      (const __attribute__((address_space(1))) u32*)g,
      (__attribute__((address_space(3))) u32*)l, 16, 0, 0);
}

// ---------------------------------------------------------------------------
// Fused cast (fp32->bf16) + transpose tile worker. in: [rows, cols] fp32.
// cast_out (optional): bf16 same layout (ushort4 stores).
// tr_out: bf16 [cols, rows] (u32 = 2-element stores, coalesced along rows).
// Tile 64x64, 256 threads. tileT pad 66 (132B row, 33-bank shift).
// ---------------------------------------------------------------------------
__device__ __forceinline__ void cast_tr_tile(
    u16 (*tileT)[66], const float* __restrict__ in, u16* __restrict__ cast_out,
    u16* __restrict__ tr_out, int rows, int cols, float scale,
    int r0, int c0, int tid)
{
  // phase 1: read float4, cast, store ushort4, scatter to tileT
  {
    const int i0 = tid >> 4;          // 0..15 row group
    const int c4 = (tid & 15) * 4;    // col group of 4
    #pragma unroll
    for (int rr = 0; rr < 4; ++rr) {
      const int r = i0 + 16 * rr;
      const float4 v = *(const float4*)&in[(long)(r0 + r) * cols + c0 + c4];
      ushort4 h;
      h.x = f2bf(v.x * scale); h.y = f2bf(v.y * scale);
      h.z = f2bf(v.z * scale); h.w = f2bf(v.w * scale);
      if (cast_out)
        *(ushort4*)&cast_out[(long)(r0 + r) * cols + c0 + c4] = h;
      tileT[c4 + 0][r] = h.x;
      tileT[c4 + 1][r] = h.y;
      tileT[c4 + 2][r] = h.z;
      tileT[c4 + 3][r] = h.w;
    }
  }
  __syncthreads();

  // phase 2: write transposed, u32 (2 bf16) per store, lanes walk rows fast
  {
    const int cb = tid >> 5;          // 0..7
    const int rh = tid & 31;          // 0..31 (u32 position within 64 rows)
    #pragma unroll
    for (int m = 0; m < 8; ++m) {
      const int c = cb * 8 + m;
      const u32 pair = *(const u32*)&tileT[c][rh * 2];
      *(u32*)&tr_out[(long)(c0 + c) * rows + r0 + rh * 2] = pair;
    }
  }
}

// ---------------------------------------------------------------------------
// Single prep kernel: {rsum=0, cast_tr(x), cast_tr(W)} in one dispatch.
// Grid (16, 32, 9): z<8 -> x batch z; z=8,by<16 -> W; z=8,by==16 -> rsum.
// ---------------------------------------------------------------------------
__global__ __launch_bounds__(256)
void prep(const float* __restrict__ x, const float* __restrict__ W,
          u16* __restrict__ Xb, u16* __restrict__ XbT, u16* __restrict__ Wt,
          float* __restrict__ rsum)
{
  __shared__ u16 tileT[64][66];
  const int tid = threadIdx.x;
  const int bx = blockIdx.x, by = blockIdx.y, z = blockIdx.z;

  if (z < 8) {
    const long off = (long)z * 2048 * 1024;
    cast_tr_tile(tileT, x + off, Xb + off, XbT + off,
                 2048, 1024, 1.0f, by * 64, bx * 64, tid);
  } else if (by < 16) {
    cast_tr_tile(tileT, W, nullptr, Wt,
                 1024, 1024, 0.03125f, by * 64, bx * 64, tid);
  } else if (by == 16) {
    *(float4*)&rsum[(bx * 256 + tid) * 4] = (float4){0.f, 0.f, 0.f, 0.f};
  }
}

// ---------------------------------------------------------------------------
// NT GEMM: C[M,N] = A[M,K] * Bt[N,K]^T, bf16 inputs, fp32 accumulate.
// Block tile = (MI*32) x (NJ*32), BK=64. 4 waves in 2x2; each wave MIxNJ
// tiles of 16x16x32 MFMA. LDS staged via global_load_lds(16B) with XOR
// chunk swizzle. GROUP_M=8 pid swizzle for L2 strip reuse.
//
// Verified plateau ~823 TF at K=1024. Session evidence (R0-R7):
//  - deep-pipeline 256^2 schedules x3: null (NT=16 too short to amortize)
//  - occupancy knob (256,4): null (not register-capped)
//  - dispatch fusion: null (gap is fixed harness overhead)
//  - 32x32x16 MFMA: REGRESSION — 128B LDS row => bank = f(chunk slot only);
//    32 same-jc lanes over 8 slots = 4-way conflict (8.4M events, +25% dur).
//    The 16x16x32 pattern's per-quad jcb+lq offset spreads the wave over
//    all slots => 0 conflicts. Do not change MFMA shape at this row width.
//
// MODE 0: plain bf16 out.
// MODE 1: bf16 out = exp(acc*escale); fp32 row sums into rsum (atomics).
// MODE 2: fp32 out = acc / rsum[row] + bias[col].
// ---------------------------------------------------------------------------
#define BK 64

template<int MODE, int MI, int NJ>
__global__ __launch_bounds__(256, 3)
void gemm_nt(const u16* __restrict__ A, const u16* __restrict__ Bt,
             void* __restrict__ Cout, const float* __restrict__ bias,
             float* __restrict__ rsum,
             int M, int N, int K, int lda, int ldb, int ldc,
             long sA, long sB, long sC, float escale)
{
  constexpr int BM = MI * 32;
  constexpr int BN = NJ * 32;
  __shared__ __align__(16) u16 As[BM * BK];
  __shared__ __align__(16) u16 Bs[BN * BK];

  const int bz = blockIdx.z;
  A  += (long)bz * sA;
  Bt += (long)bz * sB;

  const int tid  = threadIdx.x;
  const int wave = tid >> 6;
  const int lane = tid & 63;

  // GROUP_M=8 swizzle
  const int nbx = gridDim.x, nby = gridDim.y;
  const int pid  = blockIdx.y * nbx + blockIdx.x;
  const int band = 8 * nbx;
  const int gid  = pid / band;
  const int fm   = gid * 8;
  const int gsz  = min(nby - fm, 8);
  const int pm   = fm + (pid % band) % gsz;
  const int pn   = (pid % band) / gsz;
  const int tileM = pm * BM;
  const int tileN = pn * BN;

  // staging: per instruction a wave covers 8 rows x 8 chunks (16B each)
  const int srow = lane >> 3;      // 0..7 row within 8-row group
  const int sj   = lane & 7;       // 0..7 dest chunk
  const int sjj  = sj ^ srow;      // swizzled source chunk

  // wave quadrant + mfma lane coords
  const int wm = (wave >> 1) * (MI * 16);
  const int wn = (wave & 1) * (NJ * 16);
  const int lc = lane & 15;        // A row / B col / C col
  const int lq = lane >> 4;        // quad

  floatx4 acc[MI][NJ];
  #pragma unroll
  for (int i = 0; i < MI; ++i)
    #pragma unroll
    for (int j = 0; j < NJ; ++j)
      acc[i][j] = (floatx4){0.f, 0.f, 0.f, 0.f};

  for (int k0 = 0; k0 < K; k0 += BK) {
    #pragma unroll
    for (int s = 0; s < MI; ++s) {
      const int rb = (wave * MI + s) * 8;
      gload_lds16(A + (long)(tileM + rb + srow) * lda + k0 + sjj * 8,
                  &As[rb * BK]);
    }
    #pragma unroll
    for (int s = 0; s < NJ; ++s) {
      const int rb = (wave * NJ + s) * 8;
      gload_lds16(Bt + (long)(tileN + rb + srow) * ldb + k0 + sjj * 8,
                  &Bs[rb * BK]);
    }
    __syncthreads();   // drains vmcnt(0) -> LDS valid

    #pragma unroll
    for (int kk = 0; kk < BK; kk += 32) {
      const int jcb = (kk >> 3) + lq;       // logical chunk for this quad
      short8 af[MI], bf[NJ];
      #pragma unroll
      for (int i = 0; i < MI; ++i) {
        const int m = wm + i * 16 + lc;
        af[i] = *(const short8*)&As[m * BK + ((jcb ^ (m & 7)) << 3)];
      }
      #pragma unroll
      for (int j = 0; j < NJ; ++j) {
        const int n = wn + j * 16 + lc;
        bf[j] = *(const short8*)&Bs[n * BK + ((jcb ^ (n & 7)) << 3)];
      }
      #pragma unroll
      for (int i = 0; i < MI; ++i)
        #pragma unroll
        for (int j = 0; j < NJ; ++j)
          acc[i][j] = __builtin_amdgcn_mfma_f32_16x16x32_bf16(
                          af[i], bf[j], acc[i][j], 0, 0, 0);
    }
    __syncthreads();   // protect LDS before next stage
  }

  // epilogue: C/D layout col = lane&15, row = quad*4 + reg
  if (MODE == 0) {
    u16* C = (u16*)Cout + (long)bz * sC;
    #pragma unroll
    for (int i = 0; i < MI; ++i) {
      const int rb = tileM + wm + i * 16 + lq * 4;
      #pragma unroll
      for (int j = 0; j < NJ; ++j) {
        const int col = tileN + wn + j * 16 + lc;
        #pragma unroll
        for (int r = 0; r < 4; ++r)
          C[(long)(rb + r) * ldc + col] = f2bf(acc[i][j][r]);
      }
    }
  } else if (MODE == 1) {
    u16* C = (u16*)Cout + (long)bz * sC;
    float* rs = rsum + (long)bz * M;
    #pragma unroll
    for (int i = 0; i < MI; ++i) {
      const int rb = tileM + wm + i * 16 + lq * 4;
      float rpart[4] = {0.f, 0.f, 0.f, 0.f};
      #pragma unroll
      for (int j = 0; j < NJ; ++j) {
        const int col = tileN + wn + j * 16 + lc;
        #pragma unroll
        for (int r = 0; r < 4; ++r) {
          float e = __expf(acc[i][j][r] * escale);
          C[(long)(rb + r) * ldc + col] = f2bf(e);
          rpart[r] += e;
        }
      }
      #pragma unroll
      for (int r = 0; r < 4; ++r) {
        float s = rpart[r];
        s += __shfl_xor(s, 1, 64);
        s += __shfl_xor(s, 2, 64);
        s += __shfl_xor(s, 4, 64);
        s += __shfl_xor(s, 8, 64);
        if (lc == 0) atomicAdd(&rs[rb + r], s);
      }
    }
  } else {
    float* C = (float*)Cout + (long)bz * sC;
    const float* rs = rsum + (long)bz * M;
    #pragma unroll
    for (int i = 0; i < MI; ++i) {
      const int rb = tileM + wm + i * 16 + lq * 4;
      float inv[4];
      #pragma unroll
      for (int r = 0; r < 4; ++r) inv[r] = 1.0f / rs[rb + r];
      #pragma unroll
      for (int j = 0; j < NJ; ++j) {
        const int col = tileN + wn + j * 16 + lc;
        const float bv = bias[col];
        #pragma unroll
        for (int r = 0; r < 4; ++r)
          C[(long)(rb + r) * ldc + col] = acc[i][j][r] * inv[r] + bv;
      }
    }
  }
}

// ---------------------------------------------------------------------------
extern "C" void kernel_launch(void* const* d_in, const int* in_sizes, int n_in,
                              void* d_out, int out_size, void* d_ws, size_t ws_size,
                              hipStream_t stream) {
  const float* x    = (const float*)d_in[0];   // [B,S,D] fp32
  const float* W    = (const float*)d_in[1];   // [D,D]   fp32
  const float* bias = (const float*)d_in[2];   // [D]     fp32
  float* out        = (float*)d_out;           // [B,S,D] fp32
  (void)in_sizes; (void)n_in; (void)out_size; (void)ws_size;

  const int B = 8, S = 2048, D = 1024;
  const long BSD = (long)B * S * D;            // 16,777,216

  // workspace layout (u16 elements): ~162 MiB + 64 KiB row sums
  u16* Xb  = (u16*)d_ws;            // [B,S,D] bf16 (x)
  u16* XbT = Xb  + BSD;             // [B,D,S] bf16 (x transposed per batch)
  u16* Qb  = XbT + BSD;             // [B,S,D] bf16 (Q, pre-scaled by 1/32)
  u16* Wt  = Qb  + BSD;             // [D,D]   bf16 (W^T * 1/sqrt(D))
  u16* Sc  = Wt  + (long)D * D;     // [B,S,S] bf16 (E = exp(scores), unnorm)
  float* rsum = (float*)(Sc + (long)B * S * S);  // [B,S] fp32 row sums

  dim3 blk(256);

  // prep: x->Xb+XbT, W->Wt (1/32 folded into Q), rsum=0 — one dispatch
  prep<<<dim3(D/64, S/64, B + 1), blk, 0, stream>>>(x, W, Xb, XbT, Wt, rsum);

  // GEMM1: Qb[BS,D] = Xb[BS,D] @ Wt[D,D]^T   (batches flattened)
  gemm_nt<0, 4, 4><<<dim3(D/128, (B*S)/128, 1), blk, 0, stream>>>(
      Xb, Wt, Qb, nullptr, nullptr, B*S, D, D, D, D, D, 0, 0, 0, 1.0f);

  // GEMM2: Sc[S,S] = exp(Qb[S,D] @ Xb[S,D]^T), rsum += row sums  per batch
  gemm_nt<1, 4, 4><<<dim3(S/128, S/128, B), blk, 0, stream>>>(
      Qb, Xb, Sc, nullptr, rsum, S, S, D, D, D, S,
      (long)S*D, (long)S*D, (long)S*S, 1.0f);

  // GEMM3: out[S,D] = (Sc/rsum)[S,S] @ XbT[D,S]^T + bias  per batch, fp32 out
  gemm_nt<2, 4, 4><<<dim3(D/128, S/128, B), blk, 0, stream>>>(
      Sc, XbT, out, bias, rsum, S, D, S, S, S, D,
      (long)S*S, (long)D*S, (long)S*D, 1.0f);
}